// Round 1
// baseline (595.603 us; speedup 1.0000x reference)
//
#include <hip/hip_runtime.h>

#define P 256
#define C 28
#define NPIX (P * P)        // 65536 pixels per image
#define NIMG 32
#define Q 7                 // float4s per pixel (28 floats)
#define BLK 448             // 64 pixels * 7 float4s; 7 waves
#define PIX_PER_BLK 64
// grid: 8 XCD-bands * 32 rows/band * 32 images * 4 col-blocks = 32768 blocks

// Fused kernel: z[b,i,j] = sum_c x[b,i,j,c] * bk[(i-c)&255, j, c]
//
// - One thread per float4 of x (channels 4q..4q+3 of one pixel): x loads fully
//   coalesced, 16 lines/instr. The irreducible 235 MB x stream is the roofline.
// - Mask shift folded into addressing: 4 scalar gathers per thread. Each of the
//   4 channels needs a different source row, so no vectorization is possible —
//   but the gathers are L2-hot (see swizzle below) and hide under the x stream.
// - i-banded XCD swizzle: blockIdx%8 (the XCD round-robin residue) selects a
//   contiguous band of 32 rows i. A band's gathers touch rows [i0-27, i0+32)
//   = 59 rows * 28,672 B = 1.7 MB < 4 MiB per-XCD L2, so mask reads hit L2.
//   (Plain %8 round-robin would give each XCD every other row -> 7 MB working
//   set -> L2 thrash to L3.) Within a band: img varies fastest so all 32
//   images reuse a row's mask lines back-to-back.
// - Partial dot4s staged in LDS; 64 threads reduce 7 partials each (stride 7,
//   gcd(7,32)=1 -> conflict-free) and store coalesced. Reduction tree is
//   identical to the previous passing kernel (same numerics).
__global__ __launch_bounds__(BLK) void codednet_fused_kernel(
    const float4* __restrict__ x4, const float* __restrict__ bk,
    float* __restrict__ out) {
    __shared__ float s[BLK];
    int t = threadIdx.x;
    int n = blockIdx.x;

    // bijective remap: n -> (xcd-band, i_loc, img, j0b)
    int xcd   = n & 7;          // XCD residue owns i in [xcd*32, xcd*32+32)
    int g     = n >> 3;         // [0, 4096)
    int i_loc = g >> 7;         // [0, 32)   slowest: sweep rows gradually
    int rem   = g & 127;
    int j0b   = rem & 3;        // [0, 4)
    int img   = rem >> 2;       // [0, 32)   fastest: back-to-back mask reuse
    int i     = (xcd << 5) + i_loc;
    int pid0  = (img << 16) + (i << 8) + (j0b << 6);   // first pixel of block

    int pix_loc = t / 7;        // 0..63 (magic-mul)
    int q       = t - pix_loc * 7;   // 0..6
    int j       = (j0b << 6) + pix_loc;
    int c0      = q << 2;       // channels c0..c0+3

    float4 a = x4[pid0 * 7 + t];     // contiguous: block covers f4s [pid0*7, pid0*7+448)

    int jc = j * C + c0;
    int r0 = (i - c0)     & (P - 1);
    int r1 = (i - c0 - 1) & (P - 1);
    int r2 = (i - c0 - 2) & (P - 1);
    int r3 = (i - c0 - 3) & (P - 1);
    float m0 = bk[r0 * (P * C) + jc];
    float m1 = bk[r1 * (P * C) + jc + 1];
    float m2 = bk[r2 * (P * C) + jc + 2];
    float m3 = bk[r3 * (P * C) + jc + 3];

    s[t] = a.x * m0 + a.y * m1 + a.z * m2 + a.w * m3;
    __syncthreads();

    if (t < PIX_PER_BLK) {
        const float* p = s + t * Q;
        float acc = ((p[0] + p[1]) + (p[2] + p[3])) + ((p[4] + p[5]) + p[6]);
        out[pid0 + t] = acc;
    }
}

extern "C" void kernel_launch(void* const* d_in, const int* in_sizes, int n_in,
                              void* d_out, int out_size, void* d_ws, size_t ws_size,
                              hipStream_t stream) {
    const float4* x4 = (const float4*)d_in[0];
    const float* bk  = (const float*)d_in[1];
    float* out = (float*)d_out;
    // 8 * 32 * 32 * 4 = 32768 blocks; shapes are fixed by the problem.
    codednet_fused_kernel<<<NIMG * P * (P / PIX_PER_BLK) / 1, BLK, 0, stream>>>(x4, bk, out);
}

// Round 2
// 333.895 us; speedup vs baseline: 1.7838x; 1.7838x over previous
//
#include <hip/hip_runtime.h>

#define P 256
#define C 28
#define NPIX (P * P)        // 65536 pixels per image
#define NIMG 32
#define Q 7                 // float4s per pixel (28 floats)
#define BLK 448             // 64 pixels * 7 float4s; 7 waves
#define PIX 64              // pixels per block (one row-segment of 64 cols)
#define MROWS C             // mask rows staged per block (channels 0..27)
#define MPITCH 65           // LDS pad: bank = (c + col) % 32 -> <=3-way, mostly 2-way (free)
#define MTILE (MROWS * PIX) // 1792 mask elements per block

// z[b,i,j] = sum_c x[b,i,j,c] * bk[(i-c)&255, j, c]
//
// One block = one (row i, 64-column) tile for ALL 32 images.
// - Mask tile (28 rows x 64 cols) is image-invariant: stage it in LDS ONCE
//   (1792 scalar gathers/block; 1.8M total vs 58.7M in the failed round-1
//   fused kernel -- that version was TA/L2-request-bound at 4.5% HBM BW).
// - Each thread then hoists its 4 mask scalars to registers; the 32-image
//   loop is just {coalesced float4 x-load (prefetched), 4 FMA, LDS write,
//   barrier, stride-7 LDS reduce, coalesced store}. x stream (235 MB) is
//   the roofline: ~40 us at ~6 TB/s.
// - XCD band swizzle: blockIdx%8 owns i in [xcd*32, xcd*32+32); that XCD's
//   bk working set is 59 rows ~1.7 MB < 4 MiB L2.
// - sred double-buffered -> one barrier per image (WAR on buffer k&1 is
//   separated from reduce-read k by barrier k+1).
// - Reduction tree identical to the verified round-0 kernel (same numerics).
__global__ __launch_bounds__(BLK) void codednet_kernel(
    const float4* __restrict__ x4, const float* __restrict__ bk,
    float* __restrict__ out) {
    __shared__ float sm[MROWS * MPITCH];
    __shared__ float sred[2][BLK];
    int t = threadIdx.x;
    int n = blockIdx.x;

    // bijective remap: n -> (xcd band, row-in-band, col-block)
    int xcd   = n & 7;
    int loc   = n >> 3;          // [0,128)
    int i_loc = loc >> 2;        // [0,32)
    int j0b   = loc & 3;         // [0,4)
    int i     = (xcd << 5) + i_loc;
    int j0    = j0b << 6;
    int pix0  = (i << 8) + j0;   // first pixel of tile, within an image

    // stage mask tile: sm[c][col] = bk[(((i-c)&255)*P + j0+col)*C + c]
#pragma unroll
    for (int k = 0; k < MTILE / BLK; ++k) {
        int idx = t + k * BLK;          // 0..1791
        int c   = idx >> 6;             // 0..27
        int col = idx & 63;
        int sr  = (i - c) & (P - 1);
        sm[c * MPITCH + col] = bk[((sr << 8) + j0 + col) * C + c];
    }
    __syncthreads();

    // per-thread mask scalars (image-invariant)
    int pix_loc = t / 7;                // 0..63 (magic-mul)
    int q       = t - pix_loc * 7;      // 0..6
    int c0      = q << 2;               // channels c0..c0+3
    float m0 = sm[(c0    ) * MPITCH + pix_loc];
    float m1 = sm[(c0 + 1) * MPITCH + pix_loc];
    float m2 = sm[(c0 + 2) * MPITCH + pix_loc];
    float m3 = sm[(c0 + 3) * MPITCH + pix_loc];

    const float4* xb = x4 + (size_t)pix0 * Q;   // block's f4s are contiguous per image
    float4 a = xb[t];                           // img 0, prefetched
    for (int img = 0; img < NIMG; ++img) {
        float4 acur = a;
        if (img + 1 < NIMG)                     // prefetch next image across the barrier
            a = xb[(size_t)(img + 1) * (NPIX * Q) + t];
        sred[img & 1][t] = acur.x * m0 + acur.y * m1 + acur.z * m2 + acur.w * m3;
        __syncthreads();
        if (t < PIX) {
            const float* p = sred[img & 1] + t * Q;  // stride 7: gcd(7,32)=1, conflict-free
            float acc = ((p[0] + p[1]) + (p[2] + p[3])) + ((p[4] + p[5]) + p[6]);
            out[img * NPIX + pix0 + t] = acc;
        }
    }
}

extern "C" void kernel_launch(void* const* d_in, const int* in_sizes, int n_in,
                              void* d_out, int out_size, void* d_ws, size_t ws_size,
                              hipStream_t stream) {
    const float4* x4 = (const float4*)d_in[0];
    const float* bk  = (const float*)d_in[1];
    float* out = (float*)d_out;
    // 8 XCD-bands * 32 rows * 4 col-blocks = 1024 blocks, 7 waves each
    codednet_kernel<<<P * (P / PIX), BLK, 0, stream>>>(x4, bk, out);
}

// Round 3
// 323.959 us; speedup vs baseline: 1.8385x; 1.0307x over previous
//
#include <hip/hip_runtime.h>

#define P 256
#define C 28
#define NPIX (P * P)        // 65536 pixels per image
#define NIMG 32
#define Q 7                 // float4s per pixel (28 floats)
#define BLK 512             // 64 pixels * 8 lanes; 8 waves -> 4 blocks/CU = 32 waves (full)
#define PIX 64              // pixels per block (one row, 64 cols)
#define MPITCH 65           // LDS pad for the staging/hoist reads
#define MTILE (C * PIX)     // 1792 mask elements per block

// z[b,i,j] = sum_c x[b,i,j,c] * bk[(i-c)&255, j, c]
//
// Round-2 post-mortem: the per-image __syncthreads forced a full
// s_waitcnt vmcnt(0) drain (compiler barrier semantics), serializing 32
// memory round-trips per block (~110 us vs 37 us roofline). This version has
// ZERO barriers in the image loop:
//
// - 8 lanes per pixel (q = lane&7). Lanes q=0..6 each load one float4
//   (channels 4q..4q+3); lane q=7 contributes 0. Channel reduction = 3
//   __shfl_xor steps within the 8-lane group -- no LDS, no barrier, so the
//   compiler is free to software-pipeline the x stream (#pragma unroll 4
//   keeps 4 images of loads in flight per thread).
// - Wave loads: 8 pixels x 7 f4s = 896 contiguous bytes (q=7 lanes masked,
//   no txns) -> fully coalesced. The idle lane costs 0 memory traffic and
//   we are memory-bound, so it's free.
// - Mask tile (28ch x 64col, image-invariant) staged in LDS once per block
//   (1792 scalar gathers, L2-hot via the XCD band swizzle: each XCD's bk
//   working set is 59 rows ~1.7 MB < 4 MiB L2), then hoisted to 4 regs.
// - Reduction tree ((p0+p1)+(p2+p3))+((p4+p5)+(p6+0)) == the verified
//   round-0 tree (p7 is exactly 0).
__global__ __launch_bounds__(BLK) void codednet_shfl_kernel(
    const float4* __restrict__ x4, const float* __restrict__ bk,
    float* __restrict__ out) {
    __shared__ float sm[C * MPITCH];
    int t = threadIdx.x;
    int n = blockIdx.x;

    // bijective remap: n -> (xcd band, row-in-band, col-block)
    int xcd   = n & 7;
    int loc   = n >> 3;          // [0,128)
    int i_loc = loc >> 2;        // [0,32)
    int j0b   = loc & 3;         // [0,4)
    int i     = (xcd << 5) + i_loc;
    int j0    = j0b << 6;
    int pix0  = (i << 8) + j0;   // first pixel of tile, within an image

    // stage mask tile: sm[c][col] = bk[(((i-c)&255)*P + j0+col)*C + c]
    for (int idx = t; idx < MTILE; idx += BLK) {
        int c   = idx >> 6;             // 0..27
        int col = idx & 63;             // 0..63
        int sr  = (i - c) & (P - 1);
        sm[c * MPITCH + col] = bk[((sr << 8) + j0 + col) * C + c];
    }
    __syncthreads();                    // the ONLY barrier

    int q       = t & 7;                // 0..7 (lane role within pixel)
    int pix_loc = t >> 3;               // 0..63
    int c0      = q << 2;               // channels c0..c0+3 (q<7)

    float m0 = 0.f, m1 = 0.f, m2 = 0.f, m3 = 0.f;
    if (q < 7) {                        // image-invariant mask scalars
        m0 = sm[(c0    ) * MPITCH + pix_loc];
        m1 = sm[(c0 + 1) * MPITCH + pix_loc];
        m2 = sm[(c0 + 2) * MPITCH + pix_loc];
        m3 = sm[(c0 + 3) * MPITCH + pix_loc];
    }

    int fbase = (pix0 + pix_loc) * Q + q;   // f4 index within an image (q<7)
    int obase = pix0 + pix_loc;

#pragma unroll 4
    for (int img = 0; img < NIMG; ++img) {
        float4 a = make_float4(0.f, 0.f, 0.f, 0.f);
        if (q < 7) a = x4[(size_t)img * (NPIX * Q) + fbase];
        float acc = a.x * m0 + a.y * m1 + a.z * m2 + a.w * m3;
        // 8-lane butterfly: masks 1,2,4 never cross the 8-lane group
        acc += __shfl_xor(acc, 1);
        acc += __shfl_xor(acc, 2);
        acc += __shfl_xor(acc, 4);
        if (q == 0) out[img * NPIX + obase] = acc;
    }
}

extern "C" void kernel_launch(void* const* d_in, const int* in_sizes, int n_in,
                              void* d_out, int out_size, void* d_ws, size_t ws_size,
                              hipStream_t stream) {
    const float4* x4 = (const float4*)d_in[0];
    const float* bk  = (const float*)d_in[1];
    float* out = (float*)d_out;
    // 8 XCD-bands * 32 rows * 4 col-blocks = 1024 blocks, 8 waves each
    codednet_shfl_kernel<<<P * (P / PIX), BLK, 0, stream>>>(x4, bk, out);
}